// Round 9
// baseline (383.605 us; speedup 1.0000x reference)
//
#include <hip/hip_runtime.h>
#include <hip/hip_bf16.h>
#include <hip/hip_cooperative_groups.h>

namespace cg = cooperative_groups;

// E=1024, H=16, P=64, B=2, S=2048. All f32 in/out.
// Six phases (algebra + bodies verified r1-r7, absmax <= 0.5):
//  P1: Wp split-K x8 partials (384) || Weff from RW (64) || lam (1)   [449 tasks]
//  P2: reduce 8 slices -> WpT bf16 hi/lo planes [192][1024]           [192 tasks]
//  P3: qkv z-fused split-K x8 -> qpart f32 slices                     [512 tasks]
//  P4: M 64-row chunks (k/v slice-reduce+bias inline) + Q plane reduce [96 tasks]
//  P5: G[b] = Meff @ Weff -> GT planes (Meff reduced inline)           [32 tasks]
//  P6: out = Q @ G via MFMA                                          [1024 tasks]
// Path A: single cooperative kernel (grid 256, grid.sync between phases).
// Path B (fallback if cooperative launch is rejected): same bodies as 6 kernels.

typedef __attribute__((ext_vector_type(8))) short short8;
typedef __attribute__((ext_vector_type(4))) float f32x4;
typedef unsigned short ushort_t;
typedef unsigned int uint_t;

__device__ inline ushort_t f2bf(float v) {
    uint_t u = __float_as_uint(v);
    return (ushort_t)((u + 0x7FFF + ((u >> 16) & 1)) >> 16);   // RNE
}
__device__ inline float bf2f(ushort_t h) { return __uint_as_float(((uint_t)h) << 16); }
__device__ inline void split2(float v, ushort_t& hi, ushort_t& lo) {
    hi = f2bf(v);
    lo = f2bf(v - bf2f(hi));
}
__device__ inline int swzA(int row, int k) { return (row * 64 + k) ^ ((row & 7) << 3); }

// ================= phase bodies (shared by megak and fallback kernels) =========

__device__ void p1_body(int t, int tid, char* smem,
    const float* WQ, const float* WK, const float* WV,
    const float* proj_w, const float* RW,
    const float* q1v, const float* k1v, const float* q2v, const float* k2v,
    const float* lam0,
    float* wppartT, float* Weff, float* lamp)
{
    int wave = tid >> 6, lane = tid & 63, rl = lane & 15, kg = lane >> 4;
    if (t < 384) {
        ushort_t* Ah = (ushort_t*)smem;
        ushort_t* Al = (ushort_t*)(smem + 8192);
        ushort_t* Bh = (ushort_t*)(smem + 16384);
        ushort_t* Bl = (ushort_t*)(smem + 24576);
        int slice = t / 48, tt = t % 48, z = tt / 16, rowblk = tt % 16;
        const float* A = ((z == 0) ? WQ : (z == 1) ? WK : WV) + (long long)rowblk * 64 * 1024;
        f32x4 acc[4] = {};
        int k0 = slice * 128;
        for (int ch = 0; ch < 2; ++ch, k0 += 64) {
            #pragma unroll
            for (int i = 0; i < 4; ++i) {
                int pos = tid + 256 * i;
                int r = pos >> 4, k4 = (pos & 15) * 4;
                float4 v = *(const float4*)&A[(long long)r * 1024 + k0 + k4];
                ushort4 h, l;
                split2(v.x, h.x, l.x); split2(v.y, h.y, l.y);
                split2(v.z, h.z, l.z); split2(v.w, h.w, l.w);
                int idx = swzA(r, k4);
                *(ushort4*)&Ah[idx] = h;
                *(ushort4*)&Al[idx] = l;
            }
            #pragma unroll
            for (int i = 0; i < 4; ++i) {
                int pos = tid + 256 * i;
                int kk = pos >> 4, n4 = (pos & 15) * 4;
                float4 v = *(const float4*)&proj_w[(long long)(k0 + kk) * 64 + n4];
                float vv[4] = {v.x, v.y, v.z, v.w};
                #pragma unroll
                for (int j = 0; j < 4; ++j) {
                    ushort_t h, l; split2(vv[j], h, l);
                    int idx = swzA(n4 + j, kk);
                    Bh[idx] = h; Bl[idx] = l;
                }
            }
            __syncthreads();
            int ar = wave * 16 + rl;
            #pragma unroll
            for (int ks = 0; ks < 2; ++ks) {
                int kb = ks * 32 + kg * 8;
                short8 ah = *(const short8*)&Ah[swzA(ar, kb)];
                short8 al = *(const short8*)&Al[swzA(ar, kb)];
                #pragma unroll
                for (int n = 0; n < 4; ++n) {
                    int bi = swzA(n * 16 + rl, kb);
                    short8 bh = *(const short8*)&Bh[bi];
                    short8 bl = *(const short8*)&Bl[bi];
                    acc[n] = __builtin_amdgcn_mfma_f32_16x16x32_bf16(ah, bh, acc[n], 0, 0, 0);
                    acc[n] = __builtin_amdgcn_mfma_f32_16x16x32_bf16(ah, bl, acc[n], 0, 0, 0);
                    acc[n] = __builtin_amdgcn_mfma_f32_16x16x32_bf16(al, bh, acc[n], 0, 0, 0);
                }
            }
            __syncthreads();
        }
        #pragma unroll
        for (int n = 0; n < 4; ++n) {
            int col = n * 16 + rl;
            float4 o = {acc[n][0], acc[n][1], acc[n][2], acc[n][3]};
            long long idx = (long long)slice * 196608 + (long long)(z * 64 + col) * 1024
                          + rowblk * 64 + wave * 16 + kg * 4;
            *(float4*)&wppartT[idx] = o;
        }
    } else if (t < 448) {
        int f4i = (t - 384) * 256 + tid;    // 16384 f4 over Weff[64][1024]
        int p = f4i >> 8, e4 = (f4i & 255) * 4;
        float4 s = {0.f, 0.f, 0.f, 0.f};
        #pragma unroll
        for (int h = 0; h < 16; ++h) {
            float4 r = *(const float4*)&RW[(long long)(h * 64 + p) * 1024 + e4];
            float m = (float)(h + 1);
            s.x += m * r.x; s.y += m * r.y; s.z += m * r.z; s.w += m * r.w;
        }
        *(float4*)&Weff[(long long)p * 1024 + e4] = s;
    } else {
        float* red = (float*)smem;
        float d1 = 0.f, d2 = 0.f;
        for (int i = tid; i < 1024; i += 256) {
            d1 += q1v[i] * k1v[i];
            d2 += q2v[i] * k2v[i];
        }
        #pragma unroll
        for (int off = 32; off > 0; off >>= 1) {
            d1 += __shfl_down(d1, off);
            d2 += __shfl_down(d2, off);
        }
        if ((tid & 63) == 0) { red[tid >> 6] = d1; red[4 + (tid >> 6)] = d2; }
        __syncthreads();
        if (tid == 0) {
            float s1 = red[0] + red[1] + red[2] + red[3];
            float s2 = red[4] + red[5] + red[6] + red[7];
            lamp[0] = expf(s1) - expf(s2) + lam0[0];
        }
    }
}

__device__ void p2_body(int t, int tid,
    const float* wppartT, ushort_t* WpThi, ushort_t* WpTlo)
{
    int idx = t * 256 + tid;                // 49152 f4 over [192][1024]
    long long off = (long long)idx * 4;
    float4 s = {0.f, 0.f, 0.f, 0.f};
    #pragma unroll
    for (int sl = 0; sl < 8; ++sl) {
        float4 m = *(const float4*)&wppartT[(long long)sl * 196608 + off];
        s.x += m.x; s.y += m.y; s.z += m.z; s.w += m.w;
    }
    ushort4 h, l;
    split2(s.x, h.x, l.x); split2(s.y, h.y, l.y);
    split2(s.z, h.z, l.z); split2(s.w, h.w, l.w);
    *(ushort4*)&WpThi[off] = h;
    *(ushort4*)&WpTlo[off] = l;
}

__device__ void p3_body(int t, int tid, char* smem,
    const float* x, const ushort_t* WpThi, const ushort_t* WpTlo,
    float* qpart)
{
    ushort_t* Ah = (ushort_t*)smem;
    ushort_t* Al = (ushort_t*)(smem + 8192);
    ushort_t (*Bh)[4096] = (ushort_t(*)[4096])(smem + 16384);
    ushort_t (*Bl)[4096] = (ushort_t(*)[4096])(smem + 40960);
    int wave = tid >> 6, lane = tid & 63, rl = lane & 15, kg = lane >> 4;
    int rowblk = t & 63, slice = t >> 6;
    long long row0 = (long long)rowblk * 64;
    f32x4 acc[3][4] = {};
    int k0 = slice * 128;
    for (int ch = 0; ch < 2; ++ch, k0 += 64) {
        #pragma unroll
        for (int i = 0; i < 4; ++i) {
            int pos = tid + 256 * i;
            int r = pos >> 4, k4 = (pos & 15) * 4;
            float4 v = *(const float4*)&x[(row0 + r) * 1024 + k0 + k4];
            ushort4 h, l;
            split2(v.x, h.x, l.x); split2(v.y, h.y, l.y);
            split2(v.z, h.z, l.z); split2(v.w, h.w, l.w);
            int idx = swzA(r, k4);
            *(ushort4*)&Ah[idx] = h;
            *(ushort4*)&Al[idx] = l;
        }
        #pragma unroll
        for (int z = 0; z < 3; ++z) {
            #pragma unroll
            for (int i = 0; i < 2; ++i) {
                int pos = tid + 256 * i;
                int n = pos >> 3, k8 = (pos & 7) * 8;
                int idx = swzA(n, k8);
                long long src = (long long)(z * 64 + n) * 1024 + k0 + k8;
                *(short8*)&Bh[z][idx] = *(const short8*)&WpThi[src];
                *(short8*)&Bl[z][idx] = *(const short8*)&WpTlo[src];
            }
        }
        __syncthreads();
        int ar = wave * 16 + rl;
        #pragma unroll
        for (int ks = 0; ks < 2; ++ks) {
            int kb = ks * 32 + kg * 8;
            short8 ah = *(const short8*)&Ah[swzA(ar, kb)];
            short8 al = *(const short8*)&Al[swzA(ar, kb)];
            #pragma unroll
            for (int z = 0; z < 3; ++z) {
                #pragma unroll
                for (int n = 0; n < 4; ++n) {
                    int bi = swzA(n * 16 + rl, kb);
                    short8 bh = *(const short8*)&Bh[z][bi];
                    short8 bl = *(const short8*)&Bl[z][bi];
                    acc[z][n] = __builtin_amdgcn_mfma_f32_16x16x32_bf16(ah, bh, acc[z][n], 0, 0, 0);
                    acc[z][n] = __builtin_amdgcn_mfma_f32_16x16x32_bf16(ah, bl, acc[z][n], 0, 0, 0);
                    acc[z][n] = __builtin_amdgcn_mfma_f32_16x16x32_bf16(al, bh, acc[z][n], 0, 0, 0);
                }
            }
        }
        __syncthreads();
    }
    #pragma unroll
    for (int z = 0; z < 3; ++z) {
        float* C = qpart + (long long)(slice * 3 + z) * 262144;
        #pragma unroll
        for (int n = 0; n < 4; ++n) {
            int col = n * 16 + rl;
            #pragma unroll
            for (int j = 0; j < 4; ++j) {
                long long row = row0 + wave * 16 + kg * 4 + j;
                C[row * 64 + col] = acc[z][n][j];
            }
        }
    }
}

__device__ void p4_body(int t, int tid, char* smem,
    const float* qpart, const float* proj_b,
    float* Mpart, ushort_t* Qhi, ushort_t* Qlo)
{
    if (t < 64) {
        float (*ksh)[68] = (float(*)[68])smem;
        float (*vsh)[68] = (float(*)[68])(smem + 17408);
        int ks = t & 31, b = t >> 5;
        long long row0 = (long long)b * 2048 + ks * 64;
        #pragma unroll
        for (int i = 0; i < 8; ++i) {
            int pos = tid + 256 * i;        // [arr(2)][row(64)][c4(16)]
            int arr = pos >> 10, rem = pos & 1023;
            int r = rem >> 4, c4 = (rem & 15) * 4;
            float4 s = *(const float4*)&proj_b[c4];
            long long off = (row0 + r) * 64 + c4;
            #pragma unroll
            for (int sl = 0; sl < 8; ++sl) {
                float4 m = *(const float4*)&qpart[(long long)(sl * 3 + 1 + arr) * 262144 + off];
                s.x += m.x; s.y += m.y; s.z += m.z; s.w += m.w;
            }
            if (arr == 0) *(float4*)&ksh[r][c4] = s;
            else          *(float4*)&vsh[r][c4] = s;
        }
        __syncthreads();
        int p = tid & 63, cgi = tid >> 6;
        float macc[16] = {};
        for (int s = 0; s < 64; ++s) {
            float vv = vsh[s][p];
            float4 k0 = *(const float4*)&ksh[s][cgi * 16];
            float4 k1 = *(const float4*)&ksh[s][cgi * 16 + 4];
            float4 k2 = *(const float4*)&ksh[s][cgi * 16 + 8];
            float4 k3 = *(const float4*)&ksh[s][cgi * 16 + 12];
            macc[0] += k0.x * vv;  macc[1] += k0.y * vv;  macc[2] += k0.z * vv;  macc[3] += k0.w * vv;
            macc[4] += k1.x * vv;  macc[5] += k1.y * vv;  macc[6] += k1.z * vv;  macc[7] += k1.w * vv;
            macc[8] += k2.x * vv;  macc[9] += k2.y * vv;  macc[10] += k2.z * vv; macc[11] += k2.w * vv;
            macc[12] += k3.x * vv; macc[13] += k3.y * vv; macc[14] += k3.z * vv; macc[15] += k3.w * vv;
        }
        float* o = Mpart + (long long)b * 131072 + (long long)ks * 4096;
        #pragma unroll
        for (int ci = 0; ci < 16; ++ci)
            o[(cgi * 16 + ci) * 64 + p] = macc[ci];
    } else {
        int qb = t - 64;                    // 32 tasks x 128 rows
        long long row0 = (long long)qb * 128;
        #pragma unroll
        for (int i = 0; i < 8; ++i) {
            int pos = tid + 256 * i;        // [row(128)][c4(16)]
            int r = pos >> 4, c4 = (pos & 15) * 4;
            float4 s = *(const float4*)&proj_b[c4];
            long long off = (row0 + r) * 64 + c4;
            #pragma unroll
            for (int sl = 0; sl < 8; ++sl) {
                float4 m = *(const float4*)&qpart[(long long)(sl * 3) * 262144 + off];
                s.x += m.x; s.y += m.y; s.z += m.z; s.w += m.w;
            }
            ushort4 h, l;
            split2(s.x, h.x, l.x); split2(s.y, h.y, l.y);
            split2(s.z, h.z, l.z); split2(s.w, h.w, l.w);
            *(ushort4*)&Qhi[off] = h;
            *(ushort4*)&Qlo[off] = l;
        }
    }
}

__device__ void p5_body(int t, int tid, char* smem,
    const float* Mpart, const float* Weff, const float* lamp,
    ushort_t* GThi, ushort_t* GTlo)
{
    float (*As)[68] = (float(*)[68])smem;
    float (*Bs)[68] = (float(*)[68])(smem + 17408);
    int colblk = t & 15, b = t >> 4;
    float lam = lamp[0];
    #pragma unroll
    for (int i = 0; i < 4; ++i) {
        int pos = tid + 256 * i;            // 1024 f4 over Meff[64 c][64 p]
        int c = pos >> 4, p4 = (pos & 15) * 4;
        float4 s = {0.f, 0.f, 0.f, 0.f};
        #pragma unroll 8
        for (int sc = 0; sc < 32; ++sc) {
            float4 m = *(const float4*)&Mpart[(long long)b * 131072 + (long long)sc * 4096 + c * 64 + p4];
            s.x += m.x; s.y += m.y; s.z += m.z; s.w += m.w;
        }
        float coef = 0.125f * (c < 32 ? 1.0f : -lam);
        s.x *= coef; s.y *= coef; s.z *= coef; s.w *= coef;
        *(float4*)&As[c][p4] = s;
    }
    #pragma unroll
    for (int i = 0; i < 4; ++i) {
        int pos = tid + 256 * i;
        int p = pos >> 4, e4 = (pos & 15) * 4;
        *(float4*)&Bs[p][e4] = *(const float4*)&Weff[(long long)p * 1024 + colblk * 64 + e4];
    }
    __syncthreads();
    int tx = tid & 15, ty = tid >> 4;
    float acc[4][4] = {};
    #pragma unroll 4
    for (int kk4 = 0; kk4 < 64; kk4 += 4) {
        float4 a4[4], b4[4];
        #pragma unroll
        for (int i = 0; i < 4; ++i) a4[i] = *(const float4*)&As[ty * 4 + i][kk4];
        #pragma unroll
        for (int r = 0; r < 4; ++r) b4[r] = *(const float4*)&Bs[kk4 + r][tx * 4];
        #pragma unroll
        for (int i = 0; i < 4; ++i) {
            acc[i][0] += a4[i].x * b4[0].x + a4[i].y * b4[1].x + a4[i].z * b4[2].x + a4[i].w * b4[3].x;
            acc[i][1] += a4[i].x * b4[0].y + a4[i].y * b4[1].y + a4[i].z * b4[2].y + a4[i].w * b4[3].y;
            acc[i][2] += a4[i].x * b4[0].z + a4[i].y * b4[1].z + a4[i].z * b4[2].z + a4[i].w * b4[3].z;
            acc[i][3] += a4[i].x * b4[0].w + a4[i].y * b4[1].w + a4[i].z * b4[2].w + a4[i].w * b4[3].w;
        }
    }
    #pragma unroll
    for (int i = 0; i < 4; ++i)
        #pragma unroll
        for (int j = 0; j < 4; ++j) {
            ushort_t h, l; split2(acc[i][j], h, l);
            long long idx = (long long)b * 65536 + (long long)(colblk * 64 + tx * 4 + j) * 64 + ty * 4 + i;
            GThi[idx] = h; GTlo[idx] = l;
        }
}

__device__ void p6_body(int t, int tid, char* smem,
    const ushort_t* Qhi, const ushort_t* Qlo,
    const ushort_t* GThi, const ushort_t* GTlo,
    float* out)
{
    ushort_t* Ah = (ushort_t*)smem;
    ushort_t* Al = (ushort_t*)(smem + 8192);
    ushort_t* Bh = (ushort_t*)(smem + 16384);
    ushort_t* Bl = (ushort_t*)(smem + 24576);
    int wave = tid >> 6, lane = tid & 63, rl = lane & 15, kg = lane >> 4;
    int rowblk = t & 31, colblk = (t >> 5) & 15, b = t >> 9;
    long long row0 = (long long)b * 2048 + rowblk * 64;
    #pragma unroll
    for (int i = 0; i < 2; ++i) {
        int pos = tid + 256 * i;
        int n = pos >> 3, k8 = (pos & 7) * 8;
        int idx = swzA(n, k8);
        long long qsrc = (row0 + n) * 64 + k8;
        long long gsrc = (long long)b * 65536 + (long long)(colblk * 64 + n) * 64 + k8;
        *(short8*)&Ah[idx] = *(const short8*)&Qhi[qsrc];
        *(short8*)&Al[idx] = *(const short8*)&Qlo[qsrc];
        *(short8*)&Bh[idx] = *(const short8*)&GThi[gsrc];
        *(short8*)&Bl[idx] = *(const short8*)&GTlo[gsrc];
    }
    __syncthreads();
    f32x4 acc[4] = {};
    int ar = wave * 16 + rl;
    #pragma unroll
    for (int ks = 0; ks < 2; ++ks) {
        int kb = ks * 32 + kg * 8;
        short8 ah = *(const short8*)&Ah[swzA(ar, kb)];
        short8 al = *(const short8*)&Al[swzA(ar, kb)];
        #pragma unroll
        for (int n = 0; n < 4; ++n) {
            int bi = swzA(n * 16 + rl, kb);
            short8 bh = *(const short8*)&Bh[bi];
            short8 bl = *(const short8*)&Bl[bi];
            acc[n] = __builtin_amdgcn_mfma_f32_16x16x32_bf16(ah, bh, acc[n], 0, 0, 0);
            acc[n] = __builtin_amdgcn_mfma_f32_16x16x32_bf16(ah, bl, acc[n], 0, 0, 0);
            acc[n] = __builtin_amdgcn_mfma_f32_16x16x32_bf16(al, bh, acc[n], 0, 0, 0);
        }
    }
    #pragma unroll
    for (int n = 0; n < 4; ++n) {
        int col = colblk * 64 + n * 16 + rl;
        #pragma unroll
        for (int j = 0; j < 4; ++j) {
            int row = rowblk * 64 + wave * 16 + kg * 4 + j;
            out[(long long)b * 2097152 + (long long)row * 1024 + col] = acc[n][j];
        }
    }
}

// ================= workspace layout =================
#define WS_PTRS(ws) \
    float* wppartT = (ws); \
    float* qpart   = (ws) + 1572864; \
    float* Mpart   = (ws) + 7864320; \
    float* Weff    = (ws) + 8126464; \
    float* lamp    = (ws) + 8192000; \
    ushort_t* ub   = (ushort_t*)((ws) + 8192016); \
    ushort_t* WpThi = ub; \
    ushort_t* WpTlo = ub + 196608; \
    ushort_t* Qhi   = ub + 393216; \
    ushort_t* Qlo   = ub + 655360; \
    ushort_t* GThi  = ub + 917504; \
    ushort_t* GTlo  = ub + 1048576;

// ================= Path A: cooperative megakernel =================
__global__ __launch_bounds__(256, 2) void megak(
    const float* __restrict__ x,
    const float* __restrict__ WQ, const float* __restrict__ WK, const float* __restrict__ WV,
    const float* __restrict__ RW, const float* __restrict__ proj_w,
    const float* __restrict__ proj_b,
    const float* __restrict__ q1v, const float* __restrict__ k1v,
    const float* __restrict__ q2v, const float* __restrict__ k2v,
    const float* __restrict__ lam0,
    float* __restrict__ ws, float* __restrict__ out)
{
    __shared__ __align__(16) char smem[65536];
    cg::grid_group grid = cg::this_grid();
    WS_PTRS(ws)
    int tid = threadIdx.x;

    for (int t = blockIdx.x; t < 449; t += gridDim.x) {
        __syncthreads();
        p1_body(t, tid, smem, WQ, WK, WV, proj_w, RW, q1v, k1v, q2v, k2v, lam0,
                wppartT, Weff, lamp);
    }
    __threadfence(); grid.sync();

    for (int t = blockIdx.x; t < 192; t += gridDim.x)
        p2_body(t, tid, wppartT, WpThi, WpTlo);
    __threadfence(); grid.sync();

    for (int t = blockIdx.x; t < 512; t += gridDim.x) {
        __syncthreads();
        p3_body(t, tid, smem, x, WpThi, WpTlo, qpart);
    }
    __threadfence(); grid.sync();

    for (int t = blockIdx.x; t < 96; t += gridDim.x) {
        __syncthreads();
        p4_body(t, tid, smem, qpart, proj_b, Mpart, Qhi, Qlo);
    }
    __threadfence(); grid.sync();

    for (int t = blockIdx.x; t < 32; t += gridDim.x) {
        __syncthreads();
        p5_body(t, tid, smem, Mpart, Weff, lamp, GThi, GTlo);
    }
    __threadfence(); grid.sync();

    for (int t = blockIdx.x; t < 1024; t += gridDim.x) {
        __syncthreads();
        p6_body(t, tid, smem, Qhi, Qlo, GThi, GTlo, out);
    }
}

// ================= Path B: fallback kernels (same bodies) =================
__global__ __launch_bounds__(256) void p1k(
    const float* WQ, const float* WK, const float* WV,
    const float* proj_w, const float* RW,
    const float* q1v, const float* k1v, const float* q2v, const float* k2v,
    const float* lam0, float* ws)
{
    __shared__ __align__(16) char smem[32768];
    WS_PTRS(ws)
    (void)qpart; (void)Mpart; (void)WpThi; (void)WpTlo; (void)Qhi; (void)Qlo; (void)GThi; (void)GTlo;
    p1_body(blockIdx.x, threadIdx.x, smem, WQ, WK, WV, proj_w, RW,
            q1v, k1v, q2v, k2v, lam0, wppartT, Weff, lamp);
}

__global__ __launch_bounds__(256) void p2k(float* ws)
{
    WS_PTRS(ws)
    (void)qpart; (void)Mpart; (void)Weff; (void)lamp; (void)Qhi; (void)Qlo; (void)GThi; (void)GTlo;
    p2_body(blockIdx.x, threadIdx.x, wppartT, WpThi, WpTlo);
}

__global__ __launch_bounds__(256) void p3k(const float* x, float* ws)
{
    __shared__ __align__(16) char smem[65536];
    WS_PTRS(ws)
    (void)wppartT; (void)Mpart; (void)Weff; (void)lamp; (void)Qhi; (void)Qlo; (void)GThi; (void)GTlo;
    p3_body(blockIdx.x, threadIdx.x, smem, x, WpThi, WpTlo, qpart);
}

__global__ __launch_bounds__(256) void p4k(const float* proj_b, float* ws)
{
    __shared__ __align__(16) char smem[34816];
    WS_PTRS(ws)
    (void)wppartT; (void)Weff; (void)lamp; (void)WpThi; (void)WpTlo; (void)GThi; (void)GTlo;
    p4_body(blockIdx.x, threadIdx.x, smem, qpart, proj_b, Mpart, Qhi, Qlo);
}

__global__ __launch_bounds__(256) void p5k(float* ws)
{
    __shared__ __align__(16) char smem[34816];
    WS_PTRS(ws)
    (void)wppartT; (void)qpart; (void)WpThi; (void)WpTlo; (void)Qhi; (void)Qlo;
    p5_body(blockIdx.x, threadIdx.x, smem, Mpart, Weff, lamp, GThi, GTlo);
}

__global__ __launch_bounds__(256) void p6k(float* ws, float* out)
{
    __shared__ __align__(16) char smem[32768];
    WS_PTRS(ws)
    (void)wppartT; (void)qpart; (void)Mpart; (void)Weff; (void)lamp; (void)WpThi; (void)WpTlo;
    p6_body(blockIdx.x, threadIdx.x, smem, Qhi, Qlo, GThi, GTlo, out);
}

// ================= launch =================
extern "C" void kernel_launch(void* const* d_in, const int* in_sizes, int n_in,
                              void* d_out, int out_size, void* d_ws, size_t ws_size,
                              hipStream_t stream)
{
    const float* x      = (const float*)d_in[0];
    const float* WQ     = (const float*)d_in[1];
    const float* WK     = (const float*)d_in[2];
    const float* WV     = (const float*)d_in[3];
    const float* RW     = (const float*)d_in[4];
    const float* proj_w = (const float*)d_in[5];
    const float* proj_b = (const float*)d_in[6];
    const float* q1v    = (const float*)d_in[7];
    const float* k1v    = (const float*)d_in[8];
    const float* q2v    = (const float*)d_in[9];
    const float* k2v    = (const float*)d_in[10];
    const float* lam0   = (const float*)d_in[11];
    float* ws  = (float*)d_ws;
    float* out = (float*)d_out;

    void* args[] = {
        (void*)&x, (void*)&WQ, (void*)&WK, (void*)&WV, (void*)&RW,
        (void*)&proj_w, (void*)&proj_b,
        (void*)&q1v, (void*)&k1v, (void*)&q2v, (void*)&k2v, (void*)&lam0,
        (void*)&ws, (void*)&out
    };
    hipError_t err = hipLaunchCooperativeKernel((const void*)megak, dim3(256), dim3(256),
                                                args, 0, stream);
    if (err != hipSuccess) {
        (void)hipGetLastError();   // clear sticky error, use fallback path
        dim3 blk(256);
        p1k<<<dim3(449), blk, 0, stream>>>(WQ, WK, WV, proj_w, RW,
                                           q1v, k1v, q2v, k2v, lam0, ws);
        p2k<<<dim3(192), blk, 0, stream>>>(ws);
        p3k<<<dim3(512), blk, 0, stream>>>(x, ws);
        p4k<<<dim3(96), blk, 0, stream>>>(proj_b, ws);
        p5k<<<dim3(32), blk, 0, stream>>>(ws);
        p6k<<<dim3(1024), blk, 0, stream>>>(ws, out);
    }
}

// Round 10
// 67.617 us; speedup vs baseline: 5.6732x; 5.6732x over previous
//
#include <hip/hip_runtime.h>
#include <hip/hip_bf16.h>

// E=1024, H=16, P=64, B=2, S=2048. All f32 in/out.
// Six-kernel pipeline (bodies verified r1-r9, absmax <= 0.5):
//  K1: Wp split-K x8 partials (384) || Weff from RW (64) || lam (1)   [449 blocks]
//  K2: reduce 8 slices -> WpT bf16 hi/lo planes [192][1024]           [192 blocks]
//  K3: qkv z-fused split-K x8 -> qpart f32 slices                     [512 blocks]
//  K4: M 32-row chunks (k/v slice-reduce+bias inline) + Q plane reduce [160 blocks]
//  K5: G[b] = Meff @ Weff -> GT planes (Meff reduced inline)           [32 blocks]
//  K6: out = Q @ G via MFMA                                          [1024 blocks]
// Split-bf16 MFMA: A*B ~= Ahi*Bhi + Ahi*Blo + Alo*Bhi (rel err ~1e-4).
// r9 lesson: cooperative megakernel = 399us (1 block/CU, grid.sync overhead) — dropped.

typedef __attribute__((ext_vector_type(8))) short short8;
typedef __attribute__((ext_vector_type(4))) float f32x4;
typedef unsigned short ushort_t;
typedef unsigned int uint_t;

__device__ inline ushort_t f2bf(float v) {
    uint_t u = __float_as_uint(v);
    return (ushort_t)((u + 0x7FFF + ((u >> 16) & 1)) >> 16);   // RNE
}
__device__ inline float bf2f(ushort_t h) { return __uint_as_float(((uint_t)h) << 16); }
__device__ inline void split2(float v, ushort_t& hi, ushort_t& lo) {
    hi = f2bf(v);
    lo = f2bf(v - bf2f(hi));
}
__device__ inline int swzA(int row, int k) { return (row * 64 + k) ^ ((row & 7) << 3); }

// ================= workspace layout =================
#define WS_PTRS(ws) \
    float* wppartT = (ws); \
    float* qpart   = (ws) + 1572864; \
    float* Mpart   = (ws) + 7864320; \
    float* Weff    = (ws) + 8388608; \
    float* lamp    = (ws) + 8454144; \
    ushort_t* ub   = (ushort_t*)((ws) + 8454160); \
    ushort_t* WpThi = ub; \
    ushort_t* WpTlo = ub + 196608; \
    ushort_t* Qhi   = ub + 393216; \
    ushort_t* Qlo   = ub + 655360; \
    ushort_t* GThi  = ub + 917504; \
    ushort_t* GTlo  = ub + 1048576;

// ---- K1: Wp split-K x8 partials (transposed store) + Weff + lam. grid 449.
__global__ __launch_bounds__(256) void mla_p1(
    const float* __restrict__ WQ, const float* __restrict__ WK, const float* __restrict__ WV,
    const float* __restrict__ proj_w, const float* __restrict__ RW,
    const float* __restrict__ q1v, const float* __restrict__ k1v,
    const float* __restrict__ q2v, const float* __restrict__ k2v,
    const float* __restrict__ lam0, float* __restrict__ ws)
{
    __shared__ __align__(16) char smem[32768];
    WS_PTRS(ws)
    (void)qpart; (void)Mpart; (void)WpThi; (void)WpTlo; (void)Qhi; (void)Qlo; (void)GThi; (void)GTlo;
    int t = blockIdx.x, tid = threadIdx.x;
    int wave = tid >> 6, lane = tid & 63, rl = lane & 15, kg = lane >> 4;

    if (t < 384) {
        ushort_t* Ah = (ushort_t*)smem;
        ushort_t* Al = (ushort_t*)(smem + 8192);
        ushort_t* Bh = (ushort_t*)(smem + 16384);
        ushort_t* Bl = (ushort_t*)(smem + 24576);
        int slice = t / 48, tt = t % 48, z = tt / 16, rowblk = tt % 16;
        const float* A = ((z == 0) ? WQ : (z == 1) ? WK : WV) + (long long)rowblk * 64 * 1024;
        f32x4 acc[4] = {};
        int k0 = slice * 128;
        for (int ch = 0; ch < 2; ++ch, k0 += 64) {
            #pragma unroll
            for (int i = 0; i < 4; ++i) {
                int pos = tid + 256 * i;
                int r = pos >> 4, k4 = (pos & 15) * 4;
                float4 v = *(const float4*)&A[(long long)r * 1024 + k0 + k4];
                ushort4 h, l;
                split2(v.x, h.x, l.x); split2(v.y, h.y, l.y);
                split2(v.z, h.z, l.z); split2(v.w, h.w, l.w);
                int idx = swzA(r, k4);
                *(ushort4*)&Ah[idx] = h;
                *(ushort4*)&Al[idx] = l;
            }
            #pragma unroll
            for (int i = 0; i < 4; ++i) {
                int pos = tid + 256 * i;
                int kk = pos >> 4, n4 = (pos & 15) * 4;
                float4 v = *(const float4*)&proj_w[(long long)(k0 + kk) * 64 + n4];
                float vv[4] = {v.x, v.y, v.z, v.w};
                #pragma unroll
                for (int j = 0; j < 4; ++j) {
                    ushort_t h, l; split2(vv[j], h, l);
                    int idx = swzA(n4 + j, kk);
                    Bh[idx] = h; Bl[idx] = l;
                }
            }
            __syncthreads();
            int ar = wave * 16 + rl;
            #pragma unroll
            for (int ks = 0; ks < 2; ++ks) {
                int kb = ks * 32 + kg * 8;
                short8 ah = *(const short8*)&Ah[swzA(ar, kb)];
                short8 al = *(const short8*)&Al[swzA(ar, kb)];
                #pragma unroll
                for (int n = 0; n < 4; ++n) {
                    int bi = swzA(n * 16 + rl, kb);
                    short8 bh = *(const short8*)&Bh[bi];
                    short8 bl = *(const short8*)&Bl[bi];
                    acc[n] = __builtin_amdgcn_mfma_f32_16x16x32_bf16(ah, bh, acc[n], 0, 0, 0);
                    acc[n] = __builtin_amdgcn_mfma_f32_16x16x32_bf16(ah, bl, acc[n], 0, 0, 0);
                    acc[n] = __builtin_amdgcn_mfma_f32_16x16x32_bf16(al, bh, acc[n], 0, 0, 0);
                }
            }
            __syncthreads();
        }
        #pragma unroll
        for (int n = 0; n < 4; ++n) {
            int col = n * 16 + rl;
            float4 o = {acc[n][0], acc[n][1], acc[n][2], acc[n][3]};
            long long idx = (long long)slice * 196608 + (long long)(z * 64 + col) * 1024
                          + rowblk * 64 + wave * 16 + kg * 4;
            *(float4*)&wppartT[idx] = o;
        }
    } else if (t < 448) {
        int f4i = (t - 384) * 256 + tid;    // 16384 f4 over Weff[64][1024]
        int p = f4i >> 8, e4 = (f4i & 255) * 4;
        float4 s = {0.f, 0.f, 0.f, 0.f};
        #pragma unroll
        for (int h = 0; h < 16; ++h) {
            float4 r = *(const float4*)&RW[(long long)(h * 64 + p) * 1024 + e4];
            float m = (float)(h + 1);
            s.x += m * r.x; s.y += m * r.y; s.z += m * r.z; s.w += m * r.w;
        }
        *(float4*)&Weff[(long long)p * 1024 + e4] = s;
    } else {
        float* red = (float*)smem;
        float d1 = 0.f, d2 = 0.f;
        for (int i = tid; i < 1024; i += 256) {
            d1 += q1v[i] * k1v[i];
            d2 += q2v[i] * k2v[i];
        }
        #pragma unroll
        for (int off = 32; off > 0; off >>= 1) {
            d1 += __shfl_down(d1, off);
            d2 += __shfl_down(d2, off);
        }
        if ((tid & 63) == 0) { red[tid >> 6] = d1; red[4 + (tid >> 6)] = d2; }
        __syncthreads();
        if (tid == 0) {
            float s1 = red[0] + red[1] + red[2] + red[3];
            float s2 = red[4] + red[5] + red[6] + red[7];
            lamp[0] = expf(s1) - expf(s2) + lam0[0];
        }
    }
}

// ---- K2: reduce 8 slices -> WpT planes (coalesced). grid 192.
__global__ __launch_bounds__(256) void mla_p2(float* __restrict__ ws)
{
    WS_PTRS(ws)
    (void)qpart; (void)Mpart; (void)Weff; (void)lamp; (void)Qhi; (void)Qlo; (void)GThi; (void)GTlo;
    int idx = blockIdx.x * 256 + threadIdx.x;   // 49152 f4 over [192][1024]
    long long off = (long long)idx * 4;
    float4 s = {0.f, 0.f, 0.f, 0.f};
    #pragma unroll
    for (int sl = 0; sl < 8; ++sl) {
        float4 m = *(const float4*)&wppartT[(long long)sl * 196608 + off];
        s.x += m.x; s.y += m.y; s.z += m.z; s.w += m.w;
    }
    ushort4 h, l;
    split2(s.x, h.x, l.x); split2(s.y, h.y, l.y);
    split2(s.z, h.z, l.z); split2(s.w, h.w, l.w);
    *(ushort4*)&WpThi[off] = h;
    *(ushort4*)&WpTlo[off] = l;
}

// ---- K3: qkv z-fused split-K x8. grid 512 = rowblk(64) + 64*slice(8).
__global__ __launch_bounds__(256) void mla_p3(const float* __restrict__ x, float* __restrict__ ws)
{
    __shared__ __align__(16) char smem[65536];
    WS_PTRS(ws)
    (void)wppartT; (void)Mpart; (void)Weff; (void)lamp; (void)Qhi; (void)Qlo; (void)GThi; (void)GTlo;
    ushort_t* Ah = (ushort_t*)smem;
    ushort_t* Al = (ushort_t*)(smem + 8192);
    ushort_t (*Bh)[4096] = (ushort_t(*)[4096])(smem + 16384);
    ushort_t (*Bl)[4096] = (ushort_t(*)[4096])(smem + 40960);
    int t = blockIdx.x, tid = threadIdx.x;
    int wave = tid >> 6, lane = tid & 63, rl = lane & 15, kg = lane >> 4;
    int rowblk = t & 63, slice = t >> 6;
    long long row0 = (long long)rowblk * 64;
    f32x4 acc[3][4] = {};
    int k0 = slice * 128;
    for (int ch = 0; ch < 2; ++ch, k0 += 64) {
        #pragma unroll
        for (int i = 0; i < 4; ++i) {
            int pos = tid + 256 * i;
            int r = pos >> 4, k4 = (pos & 15) * 4;
            float4 v = *(const float4*)&x[(row0 + r) * 1024 + k0 + k4];
            ushort4 h, l;
            split2(v.x, h.x, l.x); split2(v.y, h.y, l.y);
            split2(v.z, h.z, l.z); split2(v.w, h.w, l.w);
            int idx = swzA(r, k4);
            *(ushort4*)&Ah[idx] = h;
            *(ushort4*)&Al[idx] = l;
        }
        #pragma unroll
        for (int z = 0; z < 3; ++z) {
            #pragma unroll
            for (int i = 0; i < 2; ++i) {
                int pos = tid + 256 * i;
                int n = pos >> 3, k8 = (pos & 7) * 8;
                int idx = swzA(n, k8);
                long long src = (long long)(z * 64 + n) * 1024 + k0 + k8;
                *(short8*)&Bh[z][idx] = *(const short8*)&WpThi[src];
                *(short8*)&Bl[z][idx] = *(const short8*)&WpTlo[src];
            }
        }
        __syncthreads();
        int ar = wave * 16 + rl;
        #pragma unroll
        for (int ks = 0; ks < 2; ++ks) {
            int kb = ks * 32 + kg * 8;
            short8 ah = *(const short8*)&Ah[swzA(ar, kb)];
            short8 al = *(const short8*)&Al[swzA(ar, kb)];
            #pragma unroll
            for (int z = 0; z < 3; ++z) {
                #pragma unroll
                for (int n = 0; n < 4; ++n) {
                    int bi = swzA(n * 16 + rl, kb);
                    short8 bh = *(const short8*)&Bh[z][bi];
                    short8 bl = *(const short8*)&Bl[z][bi];
                    acc[z][n] = __builtin_amdgcn_mfma_f32_16x16x32_bf16(ah, bh, acc[z][n], 0, 0, 0);
                    acc[z][n] = __builtin_amdgcn_mfma_f32_16x16x32_bf16(ah, bl, acc[z][n], 0, 0, 0);
                    acc[z][n] = __builtin_amdgcn_mfma_f32_16x16x32_bf16(al, bh, acc[z][n], 0, 0, 0);
                }
            }
        }
        __syncthreads();
    }
    #pragma unroll
    for (int z = 0; z < 3; ++z) {
        float* C = qpart + (long long)(slice * 3 + z) * 262144;
        #pragma unroll
        for (int n = 0; n < 4; ++n) {
            int col = n * 16 + rl;
            #pragma unroll
            for (int j = 0; j < 4; ++j) {
                long long row = row0 + wave * 16 + kg * 4 + j;
                C[row * 64 + col] = acc[z][n][j];
            }
        }
    }
}

// ---- K4: M 32-row chunks (128 tasks) + Q plane reduce (32 tasks). grid 160.
__global__ __launch_bounds__(256) void mla_p4(const float* __restrict__ proj_b, float* __restrict__ ws)
{
    __shared__ __align__(16) char smem[17408];
    WS_PTRS(ws)
    (void)wppartT; (void)Weff; (void)lamp; (void)WpThi; (void)WpTlo; (void)GThi; (void)GTlo;
    int t = blockIdx.x, tid = threadIdx.x;
    if (t < 128) {
        float (*ksh)[68] = (float(*)[68])smem;
        float (*vsh)[68] = (float(*)[68])(smem + 8704);
        int sc = t & 63, b = t >> 6;
        long long row0 = (long long)b * 2048 + sc * 32;
        #pragma unroll
        for (int i = 0; i < 4; ++i) {
            int pos = tid + 256 * i;        // 1024: arr(2) x r(32) x c4(16)
            int arr = pos >> 9, rem = pos & 511;
            int r = rem >> 4, c4 = (rem & 15) * 4;
            float4 s = *(const float4*)&proj_b[c4];
            long long off = (row0 + r) * 64 + c4;
            #pragma unroll
            for (int sl = 0; sl < 8; ++sl) {
                float4 m = *(const float4*)&qpart[(long long)(sl * 3 + 1 + arr) * 262144 + off];
                s.x += m.x; s.y += m.y; s.z += m.z; s.w += m.w;
            }
            if (arr == 0) *(float4*)&ksh[r][c4] = s;
            else          *(float4*)&vsh[r][c4] = s;
        }
        __syncthreads();
        int p = tid & 63, cgi = tid >> 6;
        float macc[16] = {};
        for (int s = 0; s < 32; ++s) {
            float vv = vsh[s][p];
            float4 k0 = *(const float4*)&ksh[s][cgi * 16];
            float4 k1 = *(const float4*)&ksh[s][cgi * 16 + 4];
            float4 k2 = *(const float4*)&ksh[s][cgi * 16 + 8];
            float4 k3 = *(const float4*)&ksh[s][cgi * 16 + 12];
            macc[0] += k0.x * vv;  macc[1] += k0.y * vv;  macc[2] += k0.z * vv;  macc[3] += k0.w * vv;
            macc[4] += k1.x * vv;  macc[5] += k1.y * vv;  macc[6] += k1.z * vv;  macc[7] += k1.w * vv;
            macc[8] += k2.x * vv;  macc[9] += k2.y * vv;  macc[10] += k2.z * vv; macc[11] += k2.w * vv;
            macc[12] += k3.x * vv; macc[13] += k3.y * vv; macc[14] += k3.z * vv; macc[15] += k3.w * vv;
        }
        float* o = Mpart + ((long long)b * 64 + sc) * 4096;
        #pragma unroll
        for (int ci = 0; ci < 16; ++ci)
            o[(cgi * 16 + ci) * 64 + p] = macc[ci];
    } else {
        int qb = t - 128;                   // 32 tasks x 128 rows
        long long row0 = (long long)qb * 128;
        #pragma unroll
        for (int i = 0; i < 8; ++i) {
            int pos = tid + 256 * i;        // [row(128)][c4(16)]
            int r = pos >> 4, c4 = (pos & 15) * 4;
            float4 s = *(const float4*)&proj_b[c4];
            long long off = (row0 + r) * 64 + c4;
            #pragma unroll
            for (int sl = 0; sl < 8; ++sl) {
                float4 m = *(const float4*)&qpart[(long long)(sl * 3) * 262144 + off];
                s.x += m.x; s.y += m.y; s.z += m.z; s.w += m.w;
            }
            ushort4 h, l;
            split2(s.x, h.x, l.x); split2(s.y, h.y, l.y);
            split2(s.z, h.z, l.z); split2(s.w, h.w, l.w);
            *(ushort4*)&Qhi[off] = h;
            *(ushort4*)&Qlo[off] = l;
        }
    }
}

// ---- K5: Meff reduce (64 chunks) + G GEMM -> GT planes. grid 32.
__global__ __launch_bounds__(256) void mla_p5(float* __restrict__ ws)
{
    __shared__ __align__(16) char smem[34816];
    WS_PTRS(ws)
    (void)wppartT; (void)qpart; (void)WpThi; (void)WpTlo; (void)Qhi; (void)Qlo;
    float (*As)[68] = (float(*)[68])smem;
    float (*Bs)[68] = (float(*)[68])(smem + 17408);
    int t = blockIdx.x, tid = threadIdx.x;
    int colblk = t & 15, b = t >> 4;
    float lam = lamp[0];
    #pragma unroll
    for (int i = 0; i < 4; ++i) {
        int pos = tid + 256 * i;            // 1024 f4 over Meff[64 c][64 p]
        int c = pos >> 4, p4 = (pos & 15) * 4;
        float4 s = {0.f, 0.f, 0.f, 0.f};
        #pragma unroll 8
        for (int sc = 0; sc < 64; ++sc) {
            float4 m = *(const float4*)&Mpart[((long long)b * 64 + sc) * 4096 + c * 64 + p4];
            s.x += m.x; s.y += m.y; s.z += m.z; s.w += m.w;
        }
        float coef = 0.125f * (c < 32 ? 1.0f : -lam);
        s.x *= coef; s.y *= coef; s.z *= coef; s.w *= coef;
        *(float4*)&As[c][p4] = s;
    }
    #pragma unroll
    for (int i = 0; i < 4; ++i) {
        int pos = tid + 256 * i;
        int p = pos >> 4, e4 = (pos & 15) * 4;
        *(float4*)&Bs[p][e4] = *(const float4*)&Weff[(long long)p * 1024 + colblk * 64 + e4];
    }
    __syncthreads();
    int tx = tid & 15, ty = tid >> 4;
    float acc[4][4] = {};
    #pragma unroll 4
    for (int kk4 = 0; kk4 < 64; kk4 += 4) {
        float4 a4[4], b4[4];
        #pragma unroll
        for (int i = 0; i < 4; ++i) a4[i] = *(const float4*)&As[ty * 4 + i][kk4];
        #pragma unroll
        for (int r = 0; r < 4; ++r) b4[r] = *(const float4*)&Bs[kk4 + r][tx * 4];
        #pragma unroll
        for (int i = 0; i < 4; ++i) {
            acc[i][0] += a4[i].x * b4[0].x + a4[i].y * b4[1].x + a4[i].z * b4[2].x + a4[i].w * b4[3].x;
            acc[i][1] += a4[i].x * b4[0].y + a4[i].y * b4[1].y + a4[i].z * b4[2].y + a4[i].w * b4[3].y;
            acc[i][2] += a4[i].x * b4[0].z + a4[i].y * b4[1].z + a4[i].z * b4[2].z + a4[i].w * b4[3].z;
            acc[i][3] += a4[i].x * b4[0].w + a4[i].y * b4[1].w + a4[i].z * b4[2].w + a4[i].w * b4[3].w;
        }
    }
    #pragma unroll
    for (int i = 0; i < 4; ++i)
        #pragma unroll
        for (int j = 0; j < 4; ++j) {
            ushort_t h, l; split2(acc[i][j], h, l);
            long long idx = (long long)b * 65536 + (long long)(colblk * 64 + tx * 4 + j) * 64 + ty * 4 + i;
            GThi[idx] = h; GTlo[idx] = l;
        }
}

// ---- K6: out = Q @ G. grid 1024.
__global__ __launch_bounds__(256) void mla_p6(float* __restrict__ ws, float* __restrict__ out)
{
    __shared__ __align__(16) char smem[32768];
    WS_PTRS(ws)
    (void)wppartT; (void)qpart; (void)Mpart; (void)Weff; (void)lamp; (void)WpThi; (void)WpTlo;
    ushort_t* Ah = (ushort_t*)smem;
    ushort_t* Al = (ushort_t*)(smem + 8192);
    ushort_t* Bh = (ushort_t*)(smem + 16384);
    ushort_t* Bl = (ushort_t*)(smem + 24576);
    int t = blockIdx.x, tid = threadIdx.x;
    int wave = tid >> 6, lane = tid & 63, rl = lane & 15, kg = lane >> 4;
    int rowblk = t & 31, colblk = (t >> 5) & 15, b = t >> 9;
    long long row0 = (long long)b * 2048 + rowblk * 64;
    #pragma unroll
    for (int i = 0; i < 2; ++i) {
        int pos = tid + 256 * i;
        int n = pos >> 3, k8 = (pos & 7) * 8;
        int idx = swzA(n, k8);
        long long qsrc = (row0 + n) * 64 + k8;
        long long gsrc = (long long)b * 65536 + (long long)(colblk * 64 + n) * 64 + k8;
        *(short8*)&Ah[idx] = *(const short8*)&Qhi[qsrc];
        *(short8*)&Al[idx] = *(const short8*)&Qlo[qsrc];
        *(short8*)&Bh[idx] = *(const short8*)&GThi[gsrc];
        *(short8*)&Bl[idx] = *(const short8*)&GTlo[gsrc];
    }
    __syncthreads();
    f32x4 acc[4] = {};
    int ar = wave * 16 + rl;
    #pragma unroll
    for (int ks = 0; ks < 2; ++ks) {
        int kb = ks * 32 + kg * 8;
        short8 ah = *(const short8*)&Ah[swzA(ar, kb)];
        short8 al = *(const short8*)&Al[swzA(ar, kb)];
        #pragma unroll
        for (int n = 0; n < 4; ++n) {
            int bi = swzA(n * 16 + rl, kb);
            short8 bh = *(const short8*)&Bh[bi];
            short8 bl = *(const short8*)&Bl[bi];
            acc[n] = __builtin_amdgcn_mfma_f32_16x16x32_bf16(ah, bh, acc[n], 0, 0, 0);
            acc[n] = __builtin_amdgcn_mfma_f32_16x16x32_bf16(ah, bl, acc[n], 0, 0, 0);
            acc[n] = __builtin_amdgcn_mfma_f32_16x16x32_bf16(al, bh, acc[n], 0, 0, 0);
        }
    }
    #pragma unroll
    for (int n = 0; n < 4; ++n) {
        int col = colblk * 64 + n * 16 + rl;
        #pragma unroll
        for (int j = 0; j < 4; ++j) {
            int row = rowblk * 64 + wave * 16 + kg * 4 + j;
            out[(long long)b * 2097152 + (long long)row * 1024 + col] = acc[n][j];
        }
    }
}

// ================= launch =================
extern "C" void kernel_launch(void* const* d_in, const int* in_sizes, int n_in,
                              void* d_out, int out_size, void* d_ws, size_t ws_size,
                              hipStream_t stream)
{
    const float* x      = (const float*)d_in[0];
    const float* WQ     = (const float*)d_in[1];
    const float* WK     = (const float*)d_in[2];
    const float* WV     = (const float*)d_in[3];
    const float* RW     = (const float*)d_in[4];
    const float* proj_w = (const float*)d_in[5];
    const float* proj_b = (const float*)d_in[6];
    const float* q1v    = (const float*)d_in[7];
    const float* k1v    = (const float*)d_in[8];
    const float* q2v    = (const float*)d_in[9];
    const float* k2v    = (const float*)d_in[10];
    const float* lam0   = (const float*)d_in[11];
    float* ws  = (float*)d_ws;
    float* out = (float*)d_out;

    dim3 blk(256);
    mla_p1<<<dim3(449), blk, 0, stream>>>(WQ, WK, WV, proj_w, RW,
                                          q1v, k1v, q2v, k2v, lam0, ws);
    mla_p2<<<dim3(192), blk, 0, stream>>>(ws);
    mla_p3<<<dim3(512), blk, 0, stream>>>(x, ws);
    mla_p4<<<dim3(160), blk, 0, stream>>>(proj_b, ws);
    mla_p5<<<dim3(32), blk, 0, stream>>>(ws);
    mla_p6<<<dim3(1024), blk, 0, stream>>>(ws, out);
}